// Round 10
// baseline (524.787 us; speedup 1.0000x reference)
//
#include <hip/hip_runtime.h>
#include <hip/hip_bf16.h>
#include <math.h>

#define HIDC 64
#define NLAYER 4
#define NG 512
#define M3 768
#define M2 512
#define M1 256
#define NCLS 10
#define EPSV 1e-5f
#define NB 512          // partition buckets (dst >> 8), covers n < 131072
#define EPT 16          // edges per thread in scatter tile
#define NPW 4           // nodes per wave in aggregation

typedef float f32x4 __attribute__((ext_vector_type(4)));
typedef short sh8   __attribute__((ext_vector_type(8)));

// bf16 helpers (packed 2xbf16 in a uint32)
__device__ inline unsigned bf16rne(float x){
  unsigned u = __float_as_uint(x);
  return (u + 0x7fffu + ((u >> 16) & 1u)) >> 16;
}
__device__ inline unsigned packbf2(float lo, float hi){
  return bf16rne(lo) | (bf16rne(hi) << 16);
}
__device__ inline float blo(unsigned u){ return __uint_as_float(u << 16); }
__device__ inline float bhi(unsigned u){ return __uint_as_float(u & 0xffff0000u); }

__device__ inline sh8 ldfrag(const unsigned short* p){
  union { uint4 u; sh8 s; } c;
  c.u = *(const uint4*)p;
  return c.s;
}

// ---------------- graph build ----------------
__global__ __launch_bounds__(256) void k_bhist(const int* __restrict__ dst, int E,
                                               int* __restrict__ bcnt){
  __shared__ int lc[NB];
  int tid = threadIdx.x;
  for (int i = tid; i < NB; i += 256) lc[i] = 0;
  __syncthreads();
  for (int e = blockIdx.x*256 + tid; e < E; e += gridDim.x*256)
    atomicAdd(&lc[__builtin_nontemporal_load(&dst[e]) >> 8], 1);
  __syncthreads();
  for (int i = tid; i < NB; i += 256){
    int c = lc[i];
    if (c) atomicAdd(&bcnt[i], c);
  }
}

__global__ void k_bscan(const int* __restrict__ bcnt, int* __restrict__ bofs,
                        int* __restrict__ bcursor){
  __shared__ int tmp[NB];
  int tid = threadIdx.x;       // 512 threads
  int v = bcnt[tid];
  tmp[tid] = v; __syncthreads();
  for (int ofs = 1; ofs < NB; ofs <<= 1){
    int t = (tid >= ofs) ? tmp[tid-ofs] : 0;
    __syncthreads();
    tmp[tid] += t;
    __syncthreads();
  }
  int ex = tmp[tid] - v;
  bofs[tid] = ex;
  bcursor[tid] = ex;
}

// stage entry packed: (src << 8) | (dst & 255); bucket (dst>>8) is implicit.
__global__ __launch_bounds__(256) void k_bscatter(const int* __restrict__ src,
    const int* __restrict__ dst, int E, int* __restrict__ bcursor, unsigned* __restrict__ stage){
  __shared__ int lcnt[NB];
  __shared__ int lbase[NB];
  int tid = threadIdx.x;
  int t0 = blockIdx.x*(256*EPT);
  for (int i = tid; i < NB; i += 256) lcnt[i] = 0;
  __syncthreads();
  int s_[EPT], d_[EPT];
  bool ok[EPT];
  #pragma unroll
  for (int i = 0; i < EPT; i++){
    int e = t0 + i*256 + tid;
    ok[i] = (e < E);
    int ee = ok[i] ? e : 0;
    d_[i] = __builtin_nontemporal_load(&dst[ee]);
    s_[i] = __builtin_nontemporal_load(&src[ee]);
    if (ok[i]) atomicAdd(&lcnt[d_[i] >> 8], 1);
  }
  __syncthreads();
  for (int i = tid; i < NB; i += 256){
    int c = lcnt[i];
    lbase[i] = c ? atomicAdd(&bcursor[i], c) : 0;
  }
  __syncthreads();
  #pragma unroll
  for (int i = 0; i < EPT; i++){
    if (ok[i]){
      int pos = atomicAdd(&lbase[d_[i] >> 8], 1);
      stage[pos] = ((unsigned)s_[i] << 8) | ((unsigned)d_[i] & 255u);
    }
  }
}

// One block per bucket: LDS degree histogram + intra-bucket scan -> row_start/cursor/norm.
__global__ __launch_bounds__(256) void k_deg_b(const unsigned* __restrict__ stage,
    const int* __restrict__ bofs, const int* __restrict__ bcnt,
    int* __restrict__ row_start, int* __restrict__ cursor,
    float* __restrict__ normv, int n, int E){
  __shared__ int hist[256];
  __shared__ int tmp[256];
  int b = blockIdx.x;
  int tid = threadIdx.x;
  hist[tid] = 0;
  __syncthreads();
  int st = bofs[b], en = st + bcnt[b];
  for (int i = st + tid; i < en; i += 256)
    atomicAdd(&hist[stage[i] & 255u], 1);
  __syncthreads();
  int v = hist[tid];
  tmp[tid] = v;
  __syncthreads();
  for (int o = 1; o < 256; o <<= 1){
    int t = (tid >= o) ? tmp[tid-o] : 0;
    __syncthreads();
    tmp[tid] += t;
    __syncthreads();
  }
  int node = b*256 + tid;
  if (node < n){
    int rs = st + tmp[tid] - v;
    row_start[node] = rs;
    cursor[node] = rs;
    normv[node] = rsqrtf((float)(v + 1));
  }
  if (b == 0 && tid == 0) row_start[n] = E;
}

// One block per bucket: CSR fill confined to the bucket's ~16KB col region.
__global__ __launch_bounds__(256) void k_fill_b(const unsigned* __restrict__ stage,
    const int* __restrict__ bofs, const int* __restrict__ bcnt,
    int* __restrict__ cursor, int* __restrict__ col){
  int b = blockIdx.x;
  int st = bofs[b], en = st + bcnt[b];
  for (int i = st + threadIdx.x; i < en; i += 256){
    unsigned p = stage[i];
    int node = (b << 8) | (int)(p & 255u);
    int pos = atomicAdd(&cursor[node], 1);
    col[pos] = (int)(p >> 8);
  }
}

// ---------------- weight prep: Wt[c][k] bf16 with BN scale folded; bias row ----
// (a*sc+sh)@W = a@(sc.*W) + (sh@W)  -> layers 1+ become pure bf16 GEMMs.
__global__ void k_prep(const float* __restrict__ W, const float* __restrict__ scsh,
                       unsigned short* __restrict__ Wt, float* __restrict__ bvec, int K){
  int c = threadIdx.x;    // 64 threads
  float bs = 0.f;
  for (int k = 0; k < K; k++){
    float w = W[(size_t)k*64 + c];
    float sck = scsh ? scsh[k] : 1.f;
    float shk = scsh ? scsh[64 + k] : 0.f;
    Wt[(size_t)c*K + k] = (unsigned short)bf16rne(w*sck);
    bs += shk*w;
  }
  bvec[c] = bs;
}

// ---------------- MFMA epilogue: U[r][c] = bf16((acc + bias[c]) * norm[r]) -------
// C/D layout 16x16x32: col = lane&15, row = (lane>>4)*4 + reg  [guide §3, m89].
__device__ inline void mfma_epi(f32x4 acc[2][4], int rowbase, int lr, int lk,
    const float* __restrict__ norm, const float* __restrict__ bias,
    unsigned short* __restrict__ Ub, int n){
  #pragma unroll
  for (int m = 0; m < 2; m++){
    #pragma unroll
    for (int j = 0; j < 4; j++){
      int row = rowbase + m*16 + lk*4 + j;
      if (row < n){
        float nr = norm[row];
        #pragma unroll
        for (int ct = 0; ct < 4; ct++){
          int colv = ct*16 + lr;
          float v = acc[m][ct][j];
          if (bias) v += bias[colv];
          Ub[(size_t)row*64 + colv] = (unsigned short)bf16rne(v*nr);
        }
      }
    }
  }
}

// ---------------- layer-0 GEMM: U = (x @ W0)*norm, x fp32 staged->bf16 LDS -------
// 4 waves x (32 rows x 64 cols); A frags via ds_read_b128 (stride-40 rows,
// <=2-way conflicts = free); B frags from 16KB Wt (L1-hot); 8 MFMA/wave/kc.
__global__ __launch_bounds__(256) void k_gemm_l0_mfma(const float* __restrict__ X,
    const unsigned short* __restrict__ Wt, const float* __restrict__ norm,
    unsigned* __restrict__ U32, int n){
  __shared__ unsigned short Al[128*40];
  int tid = threadIdx.x;
  int w = tid >> 6, l = tid & 63;
  int lr = l & 15, lk = l >> 4;
  int rb = blockIdx.x * 128;
  f32x4 z = {0.f,0.f,0.f,0.f};
  f32x4 acc[2][4];
  #pragma unroll
  for (int m = 0; m < 2; m++)
    #pragma unroll
    for (int ct = 0; ct < 4; ct++) acc[m][ct] = z;
  for (int kc = 0; kc < 128; kc += 32){
    __syncthreads();
    { // stage 128 rows x 32 k: fp32 -> bf16
      int r = tid >> 1, h = tid & 1;
      int rr = rb + r; if (rr >= n) rr = n - 1;
      const float* xp = X + (size_t)rr*128 + kc + h*16;
      float4 v0 = *(const float4*)(xp+0);
      float4 v1 = *(const float4*)(xp+4);
      float4 v2 = *(const float4*)(xp+8);
      float4 v3 = *(const float4*)(xp+12);
      uint4 o0, o1;
      o0.x = packbf2(v0.x, v0.y); o0.y = packbf2(v0.z, v0.w);
      o0.z = packbf2(v1.x, v1.y); o0.w = packbf2(v1.z, v1.w);
      o1.x = packbf2(v2.x, v2.y); o1.y = packbf2(v2.z, v2.w);
      o1.z = packbf2(v3.x, v3.y); o1.w = packbf2(v3.z, v3.w);
      unsigned short* dl = &Al[r*40 + h*16];
      *(uint4*)(dl) = o0;
      *(uint4*)(dl+8) = o1;
    }
    __syncthreads();
    sh8 bfr[4];
    #pragma unroll
    for (int ct = 0; ct < 4; ct++)
      bfr[ct] = ldfrag(&Wt[(size_t)(ct*16+lr)*128 + kc + lk*8]);
    #pragma unroll
    for (int m = 0; m < 2; m++){
      sh8 af = ldfrag(&Al[(w*32 + m*16 + lr)*40 + lk*8]);
      #pragma unroll
      for (int ct = 0; ct < 4; ct++)
        acc[m][ct] = __builtin_amdgcn_mfma_f32_16x16x32_bf16(af, bfr[ct], acc[m][ct], 0, 0, 0);
    }
  }
  mfma_epi(acc, rb + w*32, lr, lk, norm, nullptr, (unsigned short*)U32, n);
}

// ---------------- layers 1+ GEMM: A bf16 direct from global, BN pre-folded -------
__global__ __launch_bounds__(256) void k_gemm_lb_mfma(const unsigned short* __restrict__ Ab,
    const unsigned short* __restrict__ Wt, const float* __restrict__ bias,
    const float* __restrict__ norm, unsigned* __restrict__ U32, int n){
  int tid = threadIdx.x;
  int w = tid >> 6, l = tid & 63;
  int lr = l & 15, lk = l >> 4;
  int rb = blockIdx.x * 128 + w*32;
  f32x4 z = {0.f,0.f,0.f,0.f};
  f32x4 acc[2][4];
  #pragma unroll
  for (int m = 0; m < 2; m++)
    #pragma unroll
    for (int ct = 0; ct < 4; ct++) acc[m][ct] = z;
  #pragma unroll
  for (int kc = 0; kc < 64; kc += 32){
    sh8 bfr[4];
    #pragma unroll
    for (int ct = 0; ct < 4; ct++)
      bfr[ct] = ldfrag(&Wt[(size_t)(ct*16+lr)*64 + kc + lk*8]);
    #pragma unroll
    for (int m = 0; m < 2; m++){
      int r = rb + m*16 + lr; if (r >= n) r = n - 1;
      sh8 af = ldfrag(&Ab[(size_t)r*64 + kc + lk*8]);
      #pragma unroll
      for (int ct = 0; ct < 4; ct++)
        acc[m][ct] = __builtin_amdgcn_mfma_f32_16x16x32_bf16(af, bfr[ct], acc[m][ct], 0, 0, 0);
    }
  }
  mfma_epi(acc, rb, lr, lk, norm, bias, (unsigned short*)U32, n);
}

// ---------------- aggregation + fused BN stats ----------------
__global__ __launch_bounds__(256) void k_agg_bn(const unsigned* __restrict__ U32,
    const int* __restrict__ row_start, const int* __restrict__ col,
    const float* __restrict__ norm, unsigned* __restrict__ AGGb,
    float* __restrict__ sums8, int n){
  int tid = threadIdx.x;
  int wv = tid >> 6;
  int lane = tid & 63;
  int half = lane >> 5;
  int cl = lane & 31;
  float rs0=0.f, rs1=0.f, rq0=0.f, rq1=0.f;
  int base = blockIdx.x*(4*NPW) + wv*NPW;
  #pragma unroll
  for (int it = 0; it < NPW; ++it){
    int node = __builtin_amdgcn_readfirstlane(base + it);
    bool nv = (node < n);
    int nodec = nv ? node : 0;
    int st = row_start[nodec], en = row_start[nodec+1];
    float s0 = 0.f, s1 = 0.f;
    if (half == 0){
      unsigned u = U32[(size_t)nodec*32 + cl];
      s0 = blo(u); s1 = bhi(u);
    }
    int nit = (en - st + 15) >> 4;
    for (int i = 0; i < nit; i++){
      int k = st + i*16 + half*8;
      unsigned ua[8]; float m[8];
      #pragma unroll
      for (int j = 0; j < 8; j++){
        int kk = k + j;
        bool v = (kk < en);
        int idx = v ? kk : st;
        int jn = col[idx];
        ua[j] = U32[(size_t)jn*32 + cl];
        m[j] = v ? 1.f : 0.f;
      }
      #pragma unroll
      for (int j = 0; j < 8; j++){
        s0 += m[j]*blo(ua[j]);
        s1 += m[j]*bhi(ua[j]);
      }
    }
    s0 += __shfl_xor(s0, 32);
    s1 += __shfl_xor(s1, 32);
    if (half == 0 && nv){
      float nr = norm[node];
      s0 *= nr; s1 *= nr;
      AGGb[(size_t)node*32 + cl] = packbf2(s0, s1);
      rs0 += s0; rs1 += s1; rq0 += s0*s0; rq1 += s1*s1;
    }
  }
  __shared__ float L[4][32][4];
  if (half == 0){ L[wv][cl][0]=rs0; L[wv][cl][1]=rs1; L[wv][cl][2]=rq0; L[wv][cl][3]=rq1; }
  __syncthreads();
  if (tid < 128){
    int c2 = tid & 31, f = tid >> 5;
    float v = L[0][c2][f] + L[1][c2][f] + L[2][c2][f] + L[3][c2][f];
    int addr = ((f >= 2) ? 64 : 0) + 2*c2 + (f & 1);
    atomicAdd(&sums8[(blockIdx.x & 7)*128 + addr], v);
  }
}

// ---------------- batchnorm finalize: per-layer scale/shift ----------------
__global__ void k_bn_finalize(const float* __restrict__ sums8, const float* __restrict__ g,
                              const float* __restrict__ b, float* __restrict__ scsh, float invn){
  int c = threadIdx.x;
  float s1 = 0.f, s2 = 0.f;
  #pragma unroll
  for (int s = 0; s < 8; s++){ s1 += sums8[s*128 + c]; s2 += sums8[s*128 + 64 + c]; }
  float mean = s1*invn;
  float var = s2*invn - mean*mean;
  var = fmaxf(var, 0.f);
  float sv = g[c]*rsqrtf(var + EPSV);
  scsh[c] = sv;
  scsh[64 + c] = b[c] - mean*sv;
}

// ---------------- pooling, split 8x in the row dimension (bf16 AGG input) -------
__device__ inline int lowerb(const int* a, int n, int key){
  int lo = 0, hi = n;
  while (lo < hi){ int mid = (lo+hi) >> 1; if (a[mid] < key) lo = mid+1; else hi = mid; }
  return lo;
}

__global__ __launch_bounds__(256) void k_pool_part(const unsigned* __restrict__ AGGall,
    size_t lstride32, const float* __restrict__ bnss, const int* __restrict__ batch,
    int n, float* __restrict__ Ppart){
  int bid = blockIdx.x;
  int g = bid >> 3, sub = bid & 7;
  int c = threadIdx.x;
  int l = c >> 6, ch = c & 63;
  const unsigned* A = AGGall + (size_t)l * lstride32;
  float sc = bnss[l*128 + ch], sh = bnss[l*128 + 64 + ch];
  int hi16 = ch & 1;
  int uofs = ch >> 1;
  int st = lowerb(batch, n, g), en = lowerb(batch, n, g+1);
  int len = en - st;
  int r0 = st + (int)(((long long)sub * len) >> 3);
  int r1 = st + (int)(((long long)(sub+1) * len) >> 3);
  float s = 0.f, mx = -INFINITY;
  for (int r = r0; r < r1; r++){
    unsigned u = A[(size_t)r*32 + uofs];
    float v = hi16 ? bhi(u) : blo(u);
    v = v*sc + sh;
    s += v; mx = fmaxf(mx, v);
  }
  float* P = Ppart + (size_t)bid*512;
  P[c] = s;
  P[256 + c] = mx;
}

__global__ __launch_bounds__(256) void k_pool_comb(const float* __restrict__ Ppart,
    const int* __restrict__ batch, int n, float* __restrict__ Hg){
  int g = blockIdx.x; int c = threadIdx.x;
  float s = 0.f, mx = -INFINITY;
  #pragma unroll
  for (int sub = 0; sub < 8; sub++){
    const float* P = Ppart + (size_t)(g*8 + sub)*512;
    s += P[c];
    mx = fmaxf(mx, P[256 + c]);
  }
  int st = lowerb(batch, n, g), en = lowerb(batch, n, g+1);
  int cnt = en - st;
  float avg = s / (float)(cnt > 1 ? cnt : 1);
  float mo = (cnt > 0) ? mx : 0.f;
  Hg[(size_t)g*M3 + c]        = avg;
  Hg[(size_t)g*M3 + 256 + c]  = s;
  Hg[(size_t)g*M3 + 512 + c]  = mo;
}

// ---------------- readout BN (stats -> scale/shift) ----------------
__global__ void k_bn2(const float* __restrict__ Hg, const float* __restrict__ g,
                      const float* __restrict__ b, float* __restrict__ zsc, float* __restrict__ zsh){
  int c = blockIdx.x; int tid = threadIdx.x;  // 64 threads
  float s1 = 0.f, s2 = 0.f;
  for (int r = tid; r < NG; r += 64){
    float v = Hg[(size_t)r*M3 + c];
    s1 += v; s2 += v*v;
  }
  for (int o = 32; o > 0; o >>= 1){ s1 += __shfl_down(s1, o); s2 += __shfl_down(s2, o); }
  if (tid == 0){
    float mean = s1/(float)NG;
    float var = s2/(float)NG - mean*mean;
    var = fmaxf(var, 0.f);
    float sc = g[c]*rsqrtf(var + EPSV);
    zsc[c] = sc;
    zsh[c] = b[c] - mean*sc;
  }
}

// ---------------- tiled readout GEMM (32x32 tile, 2x2/thread) ----------------
__global__ __launch_bounds__(256) void k_gemm_t(const float* __restrict__ A, int K,
    const float* __restrict__ W, int N, const float* __restrict__ bias,
    const float* __restrict__ zsc, const float* __restrict__ zsh,
    float* __restrict__ out, int relu, int applybn){
  __shared__ float As[32][36];
  __shared__ float Bs[32][36];   // transposed: Bs[n][k]
  int tid = threadIdx.x;
  int tx = tid & 15, ty = tid >> 4;
  int rb = blockIdx.y << 5, cb = blockIdx.x << 5;
  int lr = tid >> 3;            // 0..31
  int lk = (tid & 7) << 2;      // 0,4,...,28
  float acc00=0.f, acc01=0.f, acc10=0.f, acc11=0.f;
  for (int k0 = 0; k0 < K; k0 += 32){
    float4 av = *(const float4*)&A[(size_t)(rb+lr)*K + k0 + lk];
    if (applybn){
      av.x = av.x*zsc[k0+lk+0] + zsh[k0+lk+0];
      av.y = av.y*zsc[k0+lk+1] + zsh[k0+lk+1];
      av.z = av.z*zsc[k0+lk+2] + zsh[k0+lk+2];
      av.w = av.w*zsc[k0+lk+3] + zsh[k0+lk+3];
    }
    *(float4*)&As[lr][lk] = av;
    float4 bv = *(const float4*)&W[(size_t)(k0+lr)*N + cb + lk];
    Bs[lk+0][lr] = bv.x;
    Bs[lk+1][lr] = bv.y;
    Bs[lk+2][lr] = bv.z;
    Bs[lk+3][lr] = bv.w;
    __syncthreads();
    #pragma unroll
    for (int kk = 0; kk < 32; kk += 4){
      float4 a0 = *(const float4*)&As[ty][kk];
      float4 a1 = *(const float4*)&As[ty+16][kk];
      float4 b0 = *(const float4*)&Bs[tx][kk];
      float4 b1 = *(const float4*)&Bs[tx+16][kk];
      acc00 += a0.x*b0.x + a0.y*b0.y + a0.z*b0.z + a0.w*b0.w;
      acc01 += a0.x*b1.x + a0.y*b1.y + a0.z*b1.z + a0.w*b1.w;
      acc10 += a1.x*b0.x + a1.y*b0.y + a1.z*b0.z + a1.w*b0.w;
      acc11 += a1.x*b1.x + a1.y*b1.y + a1.z*b1.z + a1.w*b1.w;
    }
    __syncthreads();
  }
  int c0 = cb + tx, c1 = cb + tx + 16;
  float bz0 = bias[c0], bz1 = bias[c1];
  acc00 += bz0; acc01 += bz1; acc10 += bz0; acc11 += bz1;
  if (relu){
    acc00 = fmaxf(acc00, 0.f); acc01 = fmaxf(acc01, 0.f);
    acc10 = fmaxf(acc10, 0.f); acc11 = fmaxf(acc11, 0.f);
  }
  out[(size_t)(rb+ty)*N + c0]      = acc00;
  out[(size_t)(rb+ty)*N + c1]      = acc01;
  out[(size_t)(rb+ty+16)*N + c0]   = acc10;
  out[(size_t)(rb+ty+16)*N + c1]   = acc11;
}

// ---------------- final tiny GEMM (K=256, N=10) fused with log-softmax --------
__global__ __launch_bounds__(256) void k_gemm3_lsm(const float* __restrict__ A,
    const float* __restrict__ W, const float* __restrict__ bias, float* __restrict__ out){
  __shared__ float Wl[M1*NCLS];       // 10 KB
  __shared__ float part[64][4][NCLS]; // 10 KB
  int tid = threadIdx.x;
  for (int i = tid; i < M1*NCLS; i += 256) Wl[i] = W[i];
  __syncthreads();
  int r = blockIdx.x*64 + (tid >> 2);
  int q = tid & 3;
  float acc[NCLS];
  #pragma unroll
  for (int j = 0; j < NCLS; j++) acc[j] = 0.f;
  const float4* A4 = (const float4*)(A + (size_t)r*M1 + q*64);
  for (int kq = 0; kq < 16; kq++){
    float4 a = A4[kq];
    int kb = q*64 + kq*4;
    #pragma unroll
    for (int j = 0; j < NCLS; j++){
      acc[j] += a.x*Wl[(kb+0)*NCLS+j] + a.y*Wl[(kb+1)*NCLS+j]
              + a.z*Wl[(kb+2)*NCLS+j] + a.w*Wl[(kb+3)*NCLS+j];
    }
  }
  #pragma unroll
  for (int j = 0; j < NCLS; j++) part[tid>>2][q][j] = acc[j];
  __syncthreads();
  if (tid < 64){
    int rr = blockIdx.x*64 + tid;
    float v[NCLS]; float m = -INFINITY;
    #pragma unroll
    for (int j = 0; j < NCLS; j++){
      v[j] = part[tid][0][j] + part[tid][1][j] + part[tid][2][j] + part[tid][3][j] + bias[j];
      m = fmaxf(m, v[j]);
    }
    float s = 0.f;
    #pragma unroll
    for (int j = 0; j < NCLS; j++) s += expf(v[j] - m);
    float ls = logf(s) + m;
    #pragma unroll
    for (int j = 0; j < NCLS; j++) out[(size_t)rr*NCLS + j] = v[j] - ls;
  }
}

// ---------------- host ----------------
extern "C" void kernel_launch(void* const* d_in, const int* in_sizes, int n_in,
                              void* d_out, int out_size, void* d_ws, size_t ws_size,
                              hipStream_t stream){
  const float* x    = (const float*)d_in[0];
  const int*   src  = (const int*)d_in[1];
  const int*   dst  = (const int*)d_in[2];
  const int*   batch= (const int*)d_in[3];
  const float* W0   = (const float*)d_in[4];
  const float* Wsm  = (const float*)d_in[5];
  const float* g_bn = (const float*)d_in[7];
  const float* b_bn = (const float*)d_in[8];
  const float* g_out= (const float*)d_in[9];
  const float* b_out= (const float*)d_in[10];
  const float* w1   = (const float*)d_in[11];
  const float* b1   = (const float*)d_in[12];
  const float* w2   = (const float*)d_in[13];
  const float* b2   = (const float*)d_in[14];
  const float* w3   = (const float*)d_in[15];
  const float* b3   = (const float*)d_in[16];

  int n = in_sizes[3];   // N_NODES
  int E = in_sizes[1];   // N_EDGES

  char* ws = (char*)d_ws;
  size_t off = 0;
  auto alloc = [&](size_t bytes) -> char* {
    char* p = ws + off;
    off += (bytes + 255) / 256 * 256;
    return p;
  };
  float* normv     = (float*)alloc((size_t)n*4);
  int*   row_start = (int*)  alloc((size_t)(n+1)*4);
  int*   cursor    = (int*)  alloc((size_t)n*4);
  int*   colA      = (int*)  alloc((size_t)E*4);
  int*   bcnt      = (int*)  alloc(NB*4);
  int*   bofs      = (int*)  alloc(NB*4);
  int*   bcursor   = (int*)  alloc(NB*4);
  unsigned* stage  = (unsigned*)alloc((size_t)E*4);       // packed (src<<8)|dst&255
  unsigned* U32    = (unsigned*)alloc((size_t)n*32*4);    // packed bf16, 128B/row
  size_t lstride32 = (size_t)n*32;                        // uints per layer buffer
  unsigned* AGGall = (unsigned*)alloc((size_t)NLAYER*lstride32*4);  // bf16 packed
  float* bnsums    = (float*)alloc(8*128*4);
  float* bnss      = (float*)alloc(NLAYER*128*4);         // per-layer [sc(64)|sh(64)]
  unsigned short* Wt = (unsigned short*)alloc((size_t)NLAYER*64*128*2); // bf16 W^T per layer
  float* bvec      = (float*)alloc(NLAYER*64*4);
  float* Ppart     = (float*)alloc((size_t)NG*8*512*4);
  float* Hg        = (float*)alloc((size_t)NG*M3*4);
  float* Z1        = (float*)alloc((size_t)NG*M2*4);
  float* Z2        = (float*)alloc((size_t)NG*M1*4);
  float* zsc       = (float*)alloc(M3*4);
  float* zsh       = (float*)alloc(M3*4);

  int nb_used = (n + 255) >> 8;          // buckets actually populated
  int gb128 = (n + 127) / 128;           // MFMA node-GEMM grid

  hipMemsetAsync(bcnt, 0, NB*4, stream);
  k_prep<<<1, 64, 0, stream>>>(W0, nullptr, Wt, bvec, 128);   // layer-0 weights
  k_bhist<<<512, 256, 0, stream>>>(dst, E, bcnt);
  k_bscan<<<1, NB, 0, stream>>>(bcnt, bofs, bcursor);
  { int tiles = (E + 256*EPT - 1)/(256*EPT);
    k_bscatter<<<tiles, 256, 0, stream>>>(src, dst, E, bcursor, stage); }
  k_deg_b<<<nb_used, 256, 0, stream>>>(stage, bofs, bcnt, row_start, cursor, normv, n, E);
  k_fill_b<<<nb_used, 256, 0, stream>>>(stage, bofs, bcnt, cursor, colA);

  float invn = 1.f / (float)n;
  int aggblocks = (n + 4*NPW - 1) / (4*NPW);
  for (int l = 0; l < NLAYER; l++){
    unsigned* AGGb = AGGall + (size_t)l*lstride32;
    if (l == 0)
      k_gemm_l0_mfma<<<gb128, 256, 0, stream>>>(x, Wt, normv, U32, n);
    else
      k_gemm_lb_mfma<<<gb128, 256, 0, stream>>>((const unsigned short*)(AGGall + (size_t)(l-1)*lstride32),
                                                Wt + (size_t)l*64*128, bvec + l*64,
                                                normv, U32, n);
    hipMemsetAsync(bnsums, 0, 8*128*4, stream);
    k_agg_bn<<<aggblocks, 256, 0, stream>>>(U32, row_start, colA, normv, AGGb, bnsums, n);
    k_bn_finalize<<<1, 64, 0, stream>>>(bnsums, g_bn + l*64, b_bn + l*64, bnss + l*128, invn);
    if (l + 1 < NLAYER)
      k_prep<<<1, 64, 0, stream>>>(Wsm + (size_t)l*64*64, bnss + l*128,
                                   Wt + (size_t)(l+1)*64*128, bvec + (l+1)*64, 64);
  }

  k_pool_part<<<NG*8, 256, 0, stream>>>(AGGall, lstride32, bnss, batch, n, Ppart);
  k_pool_comb<<<NG, 256, 0, stream>>>(Ppart, batch, n, Hg);
  k_bn2<<<M3, 64, 0, stream>>>(Hg, g_out, b_out, zsc, zsh);

  { dim3 g1(M2/32, NG/32); k_gemm_t<<<g1, 256, 0, stream>>>(Hg, M3, w1, M2, b1, zsc, zsh, Z1, 1, 1); }
  { dim3 g2(M1/32, NG/32); k_gemm_t<<<g2, 256, 0, stream>>>(Z1, M2, w2, M1, b2, nullptr, nullptr, Z2, 1, 0); }
  k_gemm3_lsm<<<NG/64, 256, 0, stream>>>(Z2, w3, b3, (float*)d_out);
}

// Round 11
// 435.741 us; speedup vs baseline: 1.2044x; 1.2044x over previous
//
#include <hip/hip_runtime.h>
#include <hip/hip_bf16.h>
#include <math.h>

#define HIDC 64
#define NLAYER 4
#define NG 512
#define M3 768
#define M2 512
#define M1 256
#define NCLS 10
#define EPSV 1e-5f
#define NB 512          // partition buckets (dst >> 8), covers n < 131072
#define EPT 16          // edges per thread in scatter tile
#define NPW 4           // nodes per wave in aggregation
#define NSH 16          // shadow copies of BN sums

typedef float f32x4 __attribute__((ext_vector_type(4)));
typedef short sh8   __attribute__((ext_vector_type(8)));

// bf16 helpers (packed 2xbf16 in a uint32)
__device__ inline unsigned bf16rne(float x){
  unsigned u = __float_as_uint(x);
  return (u + 0x7fffu + ((u >> 16) & 1u)) >> 16;
}
__device__ inline unsigned packbf2(float lo, float hi){
  return bf16rne(lo) | (bf16rne(hi) << 16);
}
__device__ inline float blo(unsigned u){ return __uint_as_float(u << 16); }
__device__ inline float bhi(unsigned u){ return __uint_as_float(u & 0xffff0000u); }

__device__ inline sh8 ldfrag(const unsigned short* p){
  union { uint4 u; sh8 s; } c;
  c.u = *(const uint4*)p;
  return c.s;
}

// ---------------- graph build ----------------
__global__ __launch_bounds__(256) void k_bhist(const int* __restrict__ dst, int E,
                                               int* __restrict__ bcnt){
  __shared__ int lc[NB];
  int tid = threadIdx.x;
  for (int i = tid; i < NB; i += 256) lc[i] = 0;
  __syncthreads();
  for (int e = blockIdx.x*256 + tid; e < E; e += gridDim.x*256)
    atomicAdd(&lc[__builtin_nontemporal_load(&dst[e]) >> 8], 1);
  __syncthreads();
  for (int i = tid; i < NB; i += 256){
    int c = lc[i];
    if (c) atomicAdd(&bcnt[i], c);
  }
}

__global__ void k_bscan(const int* __restrict__ bcnt, int* __restrict__ bofs,
                        int* __restrict__ bcursor){
  __shared__ int tmp[NB];
  int tid = threadIdx.x;       // 512 threads
  int v = bcnt[tid];
  tmp[tid] = v; __syncthreads();
  for (int ofs = 1; ofs < NB; ofs <<= 1){
    int t = (tid >= ofs) ? tmp[tid-ofs] : 0;
    __syncthreads();
    tmp[tid] += t;
    __syncthreads();
  }
  int ex = tmp[tid] - v;
  bofs[tid] = ex;
  bcursor[tid] = ex;
}

// stage entry packed: (src << 8) | (dst & 255); bucket (dst>>8) is implicit.
__global__ __launch_bounds__(256) void k_bscatter(const int* __restrict__ src,
    const int* __restrict__ dst, int E, int* __restrict__ bcursor, unsigned* __restrict__ stage){
  __shared__ int lcnt[NB];
  __shared__ int lbase[NB];
  int tid = threadIdx.x;
  int t0 = blockIdx.x*(256*EPT);
  for (int i = tid; i < NB; i += 256) lcnt[i] = 0;
  __syncthreads();
  int s_[EPT], d_[EPT];
  bool ok[EPT];
  #pragma unroll
  for (int i = 0; i < EPT; i++){
    int e = t0 + i*256 + tid;
    ok[i] = (e < E);
    int ee = ok[i] ? e : 0;
    d_[i] = __builtin_nontemporal_load(&dst[ee]);
    s_[i] = __builtin_nontemporal_load(&src[ee]);
    if (ok[i]) atomicAdd(&lcnt[d_[i] >> 8], 1);
  }
  __syncthreads();
  for (int i = tid; i < NB; i += 256){
    int c = lcnt[i];
    lbase[i] = c ? atomicAdd(&bcursor[i], c) : 0;
  }
  __syncthreads();
  #pragma unroll
  for (int i = 0; i < EPT; i++){
    if (ok[i]){
      int pos = atomicAdd(&lbase[d_[i] >> 8], 1);
      stage[pos] = ((unsigned)s_[i] << 8) | ((unsigned)d_[i] & 255u);
    }
  }
}

// One block per bucket: LDS degree histogram + intra-bucket scan -> row_start/cursor/norm.
__global__ __launch_bounds__(256) void k_deg_b(const unsigned* __restrict__ stage,
    const int* __restrict__ bofs, const int* __restrict__ bcnt,
    int* __restrict__ row_start, int* __restrict__ cursor,
    float* __restrict__ normv, int n, int E){
  __shared__ int hist[256];
  __shared__ int tmp[256];
  int b = blockIdx.x;
  int tid = threadIdx.x;
  hist[tid] = 0;
  __syncthreads();
  int st = bofs[b], en = st + bcnt[b];
  for (int i = st + tid; i < en; i += 256)
    atomicAdd(&hist[stage[i] & 255u], 1);
  __syncthreads();
  int v = hist[tid];
  tmp[tid] = v;
  __syncthreads();
  for (int o = 1; o < 256; o <<= 1){
    int t = (tid >= o) ? tmp[tid-o] : 0;
    __syncthreads();
    tmp[tid] += t;
    __syncthreads();
  }
  int node = b*256 + tid;
  if (node < n){
    int rs = st + tmp[tid] - v;
    row_start[node] = rs;
    cursor[node] = rs;
    normv[node] = rsqrtf((float)(v + 1));
  }
  if (b == 0 && tid == 0) row_start[n] = E;
}

// One block per bucket: CSR fill confined to the bucket's ~16KB col region.
__global__ __launch_bounds__(256) void k_fill_b(const unsigned* __restrict__ stage,
    const int* __restrict__ bofs, const int* __restrict__ bcnt,
    int* __restrict__ cursor, int* __restrict__ col){
  int b = blockIdx.x;
  int st = bofs[b], en = st + bcnt[b];
  for (int i = st + threadIdx.x; i < en; i += 256){
    unsigned p = stage[i];
    int node = (b << 8) | (int)(p & 255u);
    int pos = atomicAdd(&cursor[node], 1);
    col[pos] = (int)(p >> 8);
  }
}

// ---------------- layer-0 weight prep: Wt[c][k] = bf16(W0[k][c]), parallel ------
// (r10 post-mortem: the 64-thread serial-K prep was 57us of pure latency)
__global__ __launch_bounds__(256) void k_prep0(const float* __restrict__ W,
    unsigned short* __restrict__ Wt){
  int tid = threadIdx.x;
  int c = tid & 63, q = tid >> 6;
  #pragma unroll 4
  for (int k = q*32; k < q*32 + 32; k++){
    float w = W[(size_t)k*64 + c];
    Wt[(size_t)c*128 + k] = (unsigned short)bf16rne(w);
  }
}

// ---------------- fused BN-finalize + next-layer weight fold ----------------
// tid<64: sc/sh from stats (written to bnss for pooling). Then, if W given:
// Wt[c][k] = bf16(sc[k]*W[k][c]); bvec[c] = sum_k sh[k]*W[k][c]  (K=64).
__global__ __launch_bounds__(256) void k_prep_bn(const float* __restrict__ sums,
    const float* __restrict__ g, const float* __restrict__ b, float invn,
    float* __restrict__ bnss_l, const float* __restrict__ W,
    unsigned short* __restrict__ Wt, float* __restrict__ bvec){
  __shared__ float ss[128];
  __shared__ float bred[4][64];
  int tid = threadIdx.x;
  if (tid < 64){
    float s1 = 0.f, s2 = 0.f;
    #pragma unroll
    for (int s = 0; s < NSH; s++){ s1 += sums[s*128 + tid]; s2 += sums[s*128 + 64 + tid]; }
    float mean = s1*invn;
    float var = fmaxf(s2*invn - mean*mean, 0.f);
    float sv = g[tid]*rsqrtf(var + EPSV);
    float sh = b[tid] - mean*sv;
    ss[tid] = sv; ss[64+tid] = sh;
    bnss_l[tid] = sv; bnss_l[64+tid] = sh;
  }
  __syncthreads();
  if (!W) return;
  int c = tid & 63, q = tid >> 6;
  float bs = 0.f;
  #pragma unroll 4
  for (int k = q*16; k < q*16 + 16; k++){
    float w = W[(size_t)k*64 + c];
    Wt[(size_t)c*64 + k] = (unsigned short)bf16rne(w*ss[k]);
    bs += ss[64+k]*w;
  }
  bred[q][c] = bs;
  __syncthreads();
  if (tid < 64) bvec[tid] = bred[0][tid]+bred[1][tid]+bred[2][tid]+bred[3][tid];
}

// ---------------- MFMA epilogue: U[r][c] = bf16((acc + bias[c]) * norm[r]) -------
// C/D layout 16x16x32: col = lane&15, row = (lane>>4)*4 + reg  [guide §3, m89].
__device__ inline void mfma_epi(f32x4 acc[2][4], int rowbase, int lr, int lk,
    const float* __restrict__ norm, const float* __restrict__ bias,
    unsigned short* __restrict__ Ub, int n){
  #pragma unroll
  for (int m = 0; m < 2; m++){
    #pragma unroll
    for (int j = 0; j < 4; j++){
      int row = rowbase + m*16 + lk*4 + j;
      if (row < n){
        float nr = norm[row];
        #pragma unroll
        for (int ct = 0; ct < 4; ct++){
          int colv = ct*16 + lr;
          float v = acc[m][ct][j];
          if (bias) v += bias[colv];
          Ub[(size_t)row*64 + colv] = (unsigned short)bf16rne(v*nr);
        }
      }
    }
  }
}

// ---------------- layer-0 GEMM: U = (x @ W0)*norm, x fp32 staged->bf16 LDS -------
__global__ __launch_bounds__(256) void k_gemm_l0_mfma(const float* __restrict__ X,
    const unsigned short* __restrict__ Wt, const float* __restrict__ norm,
    unsigned* __restrict__ U32, int n){
  __shared__ unsigned short Al[128*40];
  int tid = threadIdx.x;
  int w = tid >> 6, l = tid & 63;
  int lr = l & 15, lk = l >> 4;
  int rb = blockIdx.x * 128;
  f32x4 z = {0.f,0.f,0.f,0.f};
  f32x4 acc[2][4];
  #pragma unroll
  for (int m = 0; m < 2; m++)
    #pragma unroll
    for (int ct = 0; ct < 4; ct++) acc[m][ct] = z;
  for (int kc = 0; kc < 128; kc += 32){
    __syncthreads();
    { // stage 128 rows x 32 k: fp32 -> bf16
      int r = tid >> 1, h = tid & 1;
      int rr = rb + r; if (rr >= n) rr = n - 1;
      const float* xp = X + (size_t)rr*128 + kc + h*16;
      float4 v0 = *(const float4*)(xp+0);
      float4 v1 = *(const float4*)(xp+4);
      float4 v2 = *(const float4*)(xp+8);
      float4 v3 = *(const float4*)(xp+12);
      uint4 o0, o1;
      o0.x = packbf2(v0.x, v0.y); o0.y = packbf2(v0.z, v0.w);
      o0.z = packbf2(v1.x, v1.y); o0.w = packbf2(v1.z, v1.w);
      o1.x = packbf2(v2.x, v2.y); o1.y = packbf2(v2.z, v2.w);
      o1.z = packbf2(v3.x, v3.y); o1.w = packbf2(v3.z, v3.w);
      unsigned short* dl = &Al[r*40 + h*16];
      *(uint4*)(dl) = o0;
      *(uint4*)(dl+8) = o1;
    }
    __syncthreads();
    sh8 bfr[4];
    #pragma unroll
    for (int ct = 0; ct < 4; ct++)
      bfr[ct] = ldfrag(&Wt[(size_t)(ct*16+lr)*128 + kc + lk*8]);
    #pragma unroll
    for (int m = 0; m < 2; m++){
      sh8 af = ldfrag(&Al[(w*32 + m*16 + lr)*40 + lk*8]);
      #pragma unroll
      for (int ct = 0; ct < 4; ct++)
        acc[m][ct] = __builtin_amdgcn_mfma_f32_16x16x32_bf16(af, bfr[ct], acc[m][ct], 0, 0, 0);
    }
  }
  mfma_epi(acc, rb + w*32, lr, lk, norm, nullptr, (unsigned short*)U32, n);
}

// ---------------- layers 1+ GEMM: A bf16 direct from global, BN pre-folded -------
__global__ __launch_bounds__(256) void k_gemm_lb_mfma(const unsigned short* __restrict__ Ab,
    const unsigned short* __restrict__ Wt, const float* __restrict__ bias,
    const float* __restrict__ norm, unsigned* __restrict__ U32, int n){
  int tid = threadIdx.x;
  int w = tid >> 6, l = tid & 63;
  int lr = l & 15, lk = l >> 4;
  int rb = blockIdx.x * 128 + w*32;
  f32x4 z = {0.f,0.f,0.f,0.f};
  f32x4 acc[2][4];
  #pragma unroll
  for (int m = 0; m < 2; m++)
    #pragma unroll
    for (int ct = 0; ct < 4; ct++) acc[m][ct] = z;
  #pragma unroll
  for (int kc = 0; kc < 64; kc += 32){
    sh8 bfr[4];
    #pragma unroll
    for (int ct = 0; ct < 4; ct++)
      bfr[ct] = ldfrag(&Wt[(size_t)(ct*16+lr)*64 + kc + lk*8]);
    #pragma unroll
    for (int m = 0; m < 2; m++){
      int r = rb + m*16 + lr; if (r >= n) r = n - 1;
      sh8 af = ldfrag(&Ab[(size_t)r*64 + kc + lk*8]);
      #pragma unroll
      for (int ct = 0; ct < 4; ct++)
        acc[m][ct] = __builtin_amdgcn_mfma_f32_16x16x32_bf16(af, bfr[ct], acc[m][ct], 0, 0, 0);
    }
  }
  mfma_epi(acc, rb, lr, lk, norm, bias, (unsigned short*)U32, n);
}

// ---------------- aggregation + fused BN stats ----------------
__global__ __launch_bounds__(256) void k_agg_bn(const unsigned* __restrict__ U32,
    const int* __restrict__ row_start, const int* __restrict__ col,
    const float* __restrict__ norm, unsigned* __restrict__ AGGb,
    float* __restrict__ sums, int n){
  int tid = threadIdx.x;
  int wv = tid >> 6;
  int lane = tid & 63;
  int half = lane >> 5;
  int cl = lane & 31;
  float rs0=0.f, rs1=0.f, rq0=0.f, rq1=0.f;
  int base = blockIdx.x*(4*NPW) + wv*NPW;
  #pragma unroll
  for (int it = 0; it < NPW; ++it){
    int node = __builtin_amdgcn_readfirstlane(base + it);
    bool nv = (node < n);
    int nodec = nv ? node : 0;
    int st = row_start[nodec], en = row_start[nodec+1];
    float s0 = 0.f, s1 = 0.f;
    if (half == 0){
      unsigned u = U32[(size_t)nodec*32 + cl];
      s0 = blo(u); s1 = bhi(u);
    }
    int nit = (en - st + 15) >> 4;
    for (int i = 0; i < nit; i++){
      int k = st + i*16 + half*8;
      unsigned ua[8];
      #pragma unroll
      for (int j = 0; j < 8; j++){
        int kk = k + j;
        bool v = (kk < en);
        int idx = v ? kk : st;
        unsigned a = U32[(size_t)col[idx]*32 + cl];
        ua[j] = v ? a : 0u;
      }
      #pragma unroll
      for (int j = 0; j < 8; j++){
        s0 += blo(ua[j]);
        s1 += bhi(ua[j]);
      }
    }
    s0 += __shfl_xor(s0, 32);
    s1 += __shfl_xor(s1, 32);
    if (half == 0 && nv){
      float nr = norm[node];
      s0 *= nr; s1 *= nr;
      AGGb[(size_t)node*32 + cl] = packbf2(s0, s1);
      rs0 += s0; rs1 += s1; rq0 += s0*s0; rq1 += s1*s1;
    }
  }
  __shared__ float L[4][32][4];
  if (half == 0){ L[wv][cl][0]=rs0; L[wv][cl][1]=rs1; L[wv][cl][2]=rq0; L[wv][cl][3]=rq1; }
  __syncthreads();
  if (tid < 128){
    int c2 = tid & 31, f = tid >> 5;
    float v = L[0][c2][f] + L[1][c2][f] + L[2][c2][f] + L[3][c2][f];
    int addr = ((f >= 2) ? 64 : 0) + 2*c2 + (f & 1);
    atomicAdd(&sums[(blockIdx.x & (NSH-1))*128 + addr], v);
  }
}

// ---------------- pooling, split 8x in the row dimension (bf16 AGG input) -------
__device__ inline int lowerb(const int* a, int n, int key){
  int lo = 0, hi = n;
  while (lo < hi){ int mid = (lo+hi) >> 1; if (a[mid] < key) lo = mid+1; else hi = mid; }
  return lo;
}

__global__ __launch_bounds__(256) void k_pool_part(const unsigned* __restrict__ AGGall,
    size_t lstride32, const float* __restrict__ bnss, const int* __restrict__ batch,
    int n, float* __restrict__ Ppart){
  int bid = blockIdx.x;
  int g = bid >> 3, sub = bid & 7;
  int c = threadIdx.x;
  int l = c >> 6, ch = c & 63;
  const unsigned* A = AGGall + (size_t)l * lstride32;
  float sc = bnss[l*128 + ch], sh = bnss[l*128 + 64 + ch];
  int hi16 = ch & 1;
  int uofs = ch >> 1;
  int st = lowerb(batch, n, g), en = lowerb(batch, n, g+1);
  int len = en - st;
  int r0 = st + (int)(((long long)sub * len) >> 3);
  int r1 = st + (int)(((long long)(sub+1) * len) >> 3);
  float s = 0.f, mx = -INFINITY;
  for (int r = r0; r < r1; r++){
    unsigned u = A[(size_t)r*32 + uofs];
    float v = hi16 ? bhi(u) : blo(u);
    v = v*sc + sh;
    s += v; mx = fmaxf(mx, v);
  }
  float* P = Ppart + (size_t)bid*512;
  P[c] = s;
  P[256 + c] = mx;
}

__global__ __launch_bounds__(256) void k_pool_comb(const float* __restrict__ Ppart,
    const int* __restrict__ batch, int n, float* __restrict__ Hg){
  int g = blockIdx.x; int c = threadIdx.x;
  float s = 0.f, mx = -INFINITY;
  #pragma unroll
  for (int sub = 0; sub < 8; sub++){
    const float* P = Ppart + (size_t)(g*8 + sub)*512;
    s += P[c];
    mx = fmaxf(mx, P[256 + c]);
  }
  int st = lowerb(batch, n, g), en = lowerb(batch, n, g+1);
  int cnt = en - st;
  float avg = s / (float)(cnt > 1 ? cnt : 1);
  float mo = (cnt > 0) ? mx : 0.f;
  Hg[(size_t)g*M3 + c]        = avg;
  Hg[(size_t)g*M3 + 256 + c]  = s;
  Hg[(size_t)g*M3 + 512 + c]  = mo;
}

// ---------------- readout BN (stats -> scale/shift) ----------------
__global__ void k_bn2(const float* __restrict__ Hg, const float* __restrict__ g,
                      const float* __restrict__ b, float* __restrict__ zsc, float* __restrict__ zsh){
  int c = blockIdx.x; int tid = threadIdx.x;  // 64 threads
  float s1 = 0.f, s2 = 0.f;
  for (int r = tid; r < NG; r += 64){
    float v = Hg[(size_t)r*M3 + c];
    s1 += v; s2 += v*v;
  }
  for (int o = 32; o > 0; o >>= 1){ s1 += __shfl_down(s1, o); s2 += __shfl_down(s2, o); }
  if (tid == 0){
    float mean = s1/(float)NG;
    float var = s2/(float)NG - mean*mean;
    var = fmaxf(var, 0.f);
    float sc = g[c]*rsqrtf(var + EPSV);
    zsc[c] = sc;
    zsh[c] = b[c] - mean*sc;
  }
}

// ---------------- tiled readout GEMM (32x32 tile, 2x2/thread) ----------------
__global__ __launch_bounds__(256) void k_gemm_t(const float* __restrict__ A, int K,
    const float* __restrict__ W, int N, const float* __restrict__ bias,
    const float* __restrict__ zsc, const float* __restrict__ zsh,
    float* __restrict__ out, int relu, int applybn){
  __shared__ float As[32][36];
  __shared__ float Bs[32][36];   // transposed: Bs[n][k]
  int tid = threadIdx.x;
  int tx = tid & 15, ty = tid >> 4;
  int rb = blockIdx.y << 5, cb = blockIdx.x << 5;
  int lr = tid >> 3;            // 0..31
  int lk = (tid & 7) << 2;      // 0,4,...,28
  float acc00=0.f, acc01=0.f, acc10=0.f, acc11=0.f;
  for (int k0 = 0; k0 < K; k0 += 32){
    float4 av = *(const float4*)&A[(size_t)(rb+lr)*K + k0 + lk];
    if (applybn){
      av.x = av.x*zsc[k0+lk+0] + zsh[k0+lk+0];
      av.y = av.y*zsc[k0+lk+1] + zsh[k0+lk+1];
      av.z = av.z*zsc[k0+lk+2] + zsh[k0+lk+2];
      av.w = av.w*zsc[k0+lk+3] + zsh[k0+lk+3];
    }
    *(float4*)&As[lr][lk] = av;
    float4 bv = *(const float4*)&W[(size_t)(k0+lr)*N + cb + lk];
    Bs[lk+0][lr] = bv.x;
    Bs[lk+1][lr] = bv.y;
    Bs[lk+2][lr] = bv.z;
    Bs[lk+3][lr] = bv.w;
    __syncthreads();
    #pragma unroll
    for (int kk = 0; kk < 32; kk += 4){
      float4 a0 = *(const float4*)&As[ty][kk];
      float4 a1 = *(const float4*)&As[ty+16][kk];
      float4 b0 = *(const float4*)&Bs[tx][kk];
      float4 b1 = *(const float4*)&Bs[tx+16][kk];
      acc00 += a0.x*b0.x + a0.y*b0.y + a0.z*b0.z + a0.w*b0.w;
      acc01 += a0.x*b1.x + a0.y*b1.y + a0.z*b1.z + a0.w*b1.w;
      acc10 += a1.x*b0.x + a1.y*b0.y + a1.z*b0.z + a1.w*b0.w;
      acc11 += a1.x*b1.x + a1.y*b1.y + a1.z*b1.z + a1.w*b1.w;
    }
    __syncthreads();
  }
  int c0 = cb + tx, c1 = cb + tx + 16;
  float bz0 = bias[c0], bz1 = bias[c1];
  acc00 += bz0; acc01 += bz1; acc10 += bz0; acc11 += bz1;
  if (relu){
    acc00 = fmaxf(acc00, 0.f); acc01 = fmaxf(acc01, 0.f);
    acc10 = fmaxf(acc10, 0.f); acc11 = fmaxf(acc11, 0.f);
  }
  out[(size_t)(rb+ty)*N + c0]      = acc00;
  out[(size_t)(rb+ty)*N + c1]      = acc01;
  out[(size_t)(rb+ty+16)*N + c0]   = acc10;
  out[(size_t)(rb+ty+16)*N + c1]   = acc11;
}

// ---------------- final tiny GEMM (K=256, N=10) fused with log-softmax --------
__global__ __launch_bounds__(256) void k_gemm3_lsm(const float* __restrict__ A,
    const float* __restrict__ W, const float* __restrict__ bias, float* __restrict__ out){
  __shared__ float Wl[M1*NCLS];       // 10 KB
  __shared__ float part[64][4][NCLS]; // 10 KB
  int tid = threadIdx.x;
  for (int i = tid; i < M1*NCLS; i += 256) Wl[i] = W[i];
  __syncthreads();
  int r = blockIdx.x*64 + (tid >> 2);
  int q = tid & 3;
  float acc[NCLS];
  #pragma unroll
  for (int j = 0; j < NCLS; j++) acc[j] = 0.f;
  const float4* A4 = (const float4*)(A + (size_t)r*M1 + q*64);
  for (int kq = 0; kq < 16; kq++){
    float4 a = A4[kq];
    int kb = q*64 + kq*4;
    #pragma unroll
    for (int j = 0; j < NCLS; j++){
      acc[j] += a.x*Wl[(kb+0)*NCLS+j] + a.y*Wl[(kb+1)*NCLS+j]
              + a.z*Wl[(kb+2)*NCLS+j] + a.w*Wl[(kb+3)*NCLS+j];
    }
  }
  #pragma unroll
  for (int j = 0; j < NCLS; j++) part[tid>>2][q][j] = acc[j];
  __syncthreads();
  if (tid < 64){
    int rr = blockIdx.x*64 + tid;
    float v[NCLS]; float m = -INFINITY;
    #pragma unroll
    for (int j = 0; j < NCLS; j++){
      v[j] = part[tid][0][j] + part[tid][1][j] + part[tid][2][j] + part[tid][3][j] + bias[j];
      m = fmaxf(m, v[j]);
    }
    float s = 0.f;
    #pragma unroll
    for (int j = 0; j < NCLS; j++) s += expf(v[j] - m);
    float ls = logf(s) + m;
    #pragma unroll
    for (int j = 0; j < NCLS; j++) out[(size_t)rr*NCLS + j] = v[j] - ls;
  }
}

// ---------------- host ----------------
extern "C" void kernel_launch(void* const* d_in, const int* in_sizes, int n_in,
                              void* d_out, int out_size, void* d_ws, size_t ws_size,
                              hipStream_t stream){
  const float* x    = (const float*)d_in[0];
  const int*   src  = (const int*)d_in[1];
  const int*   dst  = (const int*)d_in[2];
  const int*   batch= (const int*)d_in[3];
  const float* W0   = (const float*)d_in[4];
  const float* Wsm  = (const float*)d_in[5];
  const float* g_bn = (const float*)d_in[7];
  const float* b_bn = (const float*)d_in[8];
  const float* g_out= (const float*)d_in[9];
  const float* b_out= (const float*)d_in[10];
  const float* w1   = (const float*)d_in[11];
  const float* b1   = (const float*)d_in[12];
  const float* w2   = (const float*)d_in[13];
  const float* b2   = (const float*)d_in[14];
  const float* w3   = (const float*)d_in[15];
  const float* b3   = (const float*)d_in[16];

  int n = in_sizes[3];   // N_NODES
  int E = in_sizes[1];   // N_EDGES

  char* ws = (char*)d_ws;
  size_t off = 0;
  auto alloc = [&](size_t bytes) -> char* {
    char* p = ws + off;
    off += (bytes + 255) / 256 * 256;
    return p;
  };
  float* normv     = (float*)alloc((size_t)n*4);
  int*   row_start = (int*)  alloc((size_t)(n+1)*4);
  int*   cursor    = (int*)  alloc((size_t)n*4);
  int*   colA      = (int*)  alloc((size_t)E*4);
  int*   bcnt      = (int*)  alloc(NB*4);
  int*   bofs      = (int*)  alloc(NB*4);
  int*   bcursor   = (int*)  alloc(NB*4);
  unsigned* stage  = (unsigned*)alloc((size_t)E*4);       // packed (src<<8)|dst&255
  unsigned* U32    = (unsigned*)alloc((size_t)n*32*4);    // packed bf16, 128B/row
  size_t lstride32 = (size_t)n*32;                        // uints per layer buffer
  unsigned* AGGall = (unsigned*)alloc((size_t)NLAYER*lstride32*4);  // bf16 packed
  float* bnsums    = (float*)alloc(NSH*128*4);
  float* bnss      = (float*)alloc(NLAYER*128*4);         // per-layer [sc(64)|sh(64)]
  unsigned short* Wt = (unsigned short*)alloc((size_t)NLAYER*64*128*2); // bf16 W^T per layer
  float* bvec      = (float*)alloc(NLAYER*64*4);
  float* Ppart     = (float*)alloc((size_t)NG*8*512*4);
  float* Hg        = (float*)alloc((size_t)NG*M3*4);
  float* Z1        = (float*)alloc((size_t)NG*M2*4);
  float* Z2        = (float*)alloc((size_t)NG*M1*4);
  float* zsc       = (float*)alloc(M3*4);
  float* zsh       = (float*)alloc(M3*4);

  int nb_used = (n + 255) >> 8;          // buckets actually populated
  int gb128 = (n + 127) / 128;           // MFMA node-GEMM grid

  hipMemsetAsync(bcnt, 0, NB*4, stream);
  k_prep0<<<1, 256, 0, stream>>>(W0, Wt);
  k_bhist<<<512, 256, 0, stream>>>(dst, E, bcnt);
  k_bscan<<<1, NB, 0, stream>>>(bcnt, bofs, bcursor);
  { int tiles = (E + 256*EPT - 1)/(256*EPT);
    k_bscatter<<<tiles, 256, 0, stream>>>(src, dst, E, bcursor, stage); }
  k_deg_b<<<nb_used, 256, 0, stream>>>(stage, bofs, bcnt, row_start, cursor, normv, n, E);
  k_fill_b<<<nb_used, 256, 0, stream>>>(stage, bofs, bcnt, cursor, colA);

  float invn = 1.f / (float)n;
  int aggblocks = (n + 4*NPW - 1) / (4*NPW);
  for (int l = 0; l < NLAYER; l++){
    unsigned* AGGb = AGGall + (size_t)l*lstride32;
    if (l == 0)
      k_gemm_l0_mfma<<<gb128, 256, 0, stream>>>(x, Wt, normv, U32, n);
    else
      k_gemm_lb_mfma<<<gb128, 256, 0, stream>>>((const unsigned short*)(AGGall + (size_t)(l-1)*lstride32),
                                                Wt + (size_t)l*64*128, bvec + l*64,
                                                normv, U32, n);
    hipMemsetAsync(bnsums, 0, NSH*128*4, stream);
    k_agg_bn<<<aggblocks, 256, 0, stream>>>(U32, row_start, colA, normv, AGGb, bnsums, n);
    // fused BN-finalize (+ fold next layer's weights, if any)
    if (l + 1 < NLAYER)
      k_prep_bn<<<1, 256, 0, stream>>>(bnsums, g_bn + l*64, b_bn + l*64, invn,
                                       bnss + l*128, Wsm + (size_t)l*64*64,
                                       Wt + (size_t)(l+1)*64*128, bvec + (l+1)*64);
    else
      k_prep_bn<<<1, 256, 0, stream>>>(bnsums, g_bn + l*64, b_bn + l*64, invn,
                                       bnss + l*128, nullptr, nullptr, nullptr);
  }

  k_pool_part<<<NG*8, 256, 0, stream>>>(AGGall, lstride32, bnss, batch, n, Ppart);
  k_pool_comb<<<NG, 256, 0, stream>>>(Ppart, batch, n, Hg);
  k_bn2<<<M3, 64, 0, stream>>>(Hg, g_out, b_out, zsc, zsh);

  { dim3 g1(M2/32, NG/32); k_gemm_t<<<g1, 256, 0, stream>>>(Hg, M3, w1, M2, b1, zsc, zsh, Z1, 1, 1); }
  { dim3 g2(M1/32, NG/32); k_gemm_t<<<g2, 256, 0, stream>>>(Z1, M2, w2, M1, b2, nullptr, nullptr, Z2, 1, 0); }
  k_gemm3_lsm<<<NG/64, 256, 0, stream>>>(Z2, w3, b3, (float*)d_out);
}